// Round 6
// baseline (320.966 us; speedup 1.0000x reference)
//
#include <hip/hip_runtime.h>
#include <hip/hip_bf16.h>
#include <cmath>

#define BT 8192      // B*T tokens
#define DD 1024      // model dim
#define EE 8         // experts
#define HH 2048      // hidden

typedef __attribute__((ext_vector_type(8))) short bf16x8;
typedef __attribute__((ext_vector_type(4))) float f32x4;

__device__ __forceinline__ unsigned short f2bf(float f) {
    union { float f; unsigned u; } v; v.f = f;
    unsigned r = v.u + 0x7FFFu + ((v.u >> 16) & 1u);   // RNE
    return (unsigned short)(r >> 16);
}

__device__ __forceinline__ float bf2f(unsigned short s) {
    union { unsigned u; float f; } v; v.u = ((unsigned)s) << 16;
    return v.f;
}

// tanh-form GELU via sigmoid: max |diff vs exact erf-GELU| ~5e-4
__device__ __forceinline__ float gelu_fast(float x) {
    float z = x * (1.5957691216f + 0.071354816f * x * x);
    return x / (1.f + __expf(-z));
}

// async global->LDS, 16B per lane; LDS dest = wave-uniform base + lane*16
__device__ __forceinline__ void gload16(const void* g, void* l) {
    __builtin_amdgcn_global_load_lds(
        (const __attribute__((address_space(1))) void*)g,
        (__attribute__((address_space(3))) void*)l, 16, 0, 0);
}

__device__ __forceinline__ void phase_fence_barrier() {
    __builtin_amdgcn_sched_barrier(0);
    __builtin_amdgcn_s_barrier();
    __builtin_amdgcn_sched_barrier(0);
}

// ---------------- prepass: W [E][R][C] fp32 -> WT [E][C][R] bf16 ----------------
__global__ __launch_bounds__(256) void transpose_cvt_kernel(const float* __restrict__ in,
                                                            unsigned short* __restrict__ out,
                                                            int R, int C) {
    __shared__ unsigned short t[64][66];               // pad 2 shorts: conflict-free
    int e  = blockIdx.z;
    int r0 = blockIdx.y * 64, c0 = blockIdx.x * 64;
    int tid = threadIdx.x;
    int ci = tid & 63, ri = tid >> 6;
    const float* src = in + ((size_t)e * R + r0) * C + c0;
#pragma unroll
    for (int j = 0; j < 16; ++j) {
        int r = ri + j * 4;
        t[ci][r] = f2bf(src[(size_t)r * C + ci]);      // coalesced read along C
    }
    __syncthreads();
    int r2 = (tid & 15) * 4, c2 = tid >> 4;            // c2 in 0..15
    unsigned short* dst = out + ((size_t)e * C + c0) * R + r0;
#pragma unroll
    for (int j = 0; j < 4; ++j) {
        int c = c2 + j * 16;
        ushort4 v = { t[c][r2], t[c][r2 + 1], t[c][r2 + 2], t[c][r2 + 3] };
        *(ushort4*)&dst[(size_t)c * R + r2] = v;       // coalesced write along R
    }
}

// ---------------- gating (+ fused x->bf16 convert): NO atomics ----------------
__global__ void gating_kernel(const float* __restrict__ x, const float* __restrict__ Wg,
                              const float* __restrict__ bg, int* __restrict__ tk_pack,
                              float* __restrict__ tk_w, float* __restrict__ ssq,
                              unsigned short* __restrict__ xbf) {
    int lane = threadIdx.x & 63;
    int wid  = threadIdx.x >> 6;
    int t = blockIdx.x * 4 + wid;           // one wave per token
    const float* xr = x + (size_t)t * DD;
    unsigned short* xbr = xbf + (size_t)t * DD;
    float acc[EE];
#pragma unroll
    for (int e = 0; e < EE; ++e) acc[e] = 0.f;
    for (int d = lane; d < DD; d += 64) {
        float xv = xr[d];
        xbr[d] = f2bf(xv);                  // fused convert (coalesced 128B/wave)
        const float* wr = Wg + d * EE;
#pragma unroll
        for (int e = 0; e < EE; ++e) acc[e] += xv * wr[e];
    }
#pragma unroll
    for (int off = 32; off; off >>= 1)
#pragma unroll
        for (int e = 0; e < EE; ++e) acc[e] += __shfl_xor(acc[e], off, 64);

    if (lane == 0) {
        float p[EE]; float m = -1e30f;
#pragma unroll
        for (int e = 0; e < EE; ++e) { p[e] = acc[e] + bg[e]; m = fmaxf(m, p[e]); }
        float s = 0.f;
#pragma unroll
        for (int e = 0; e < EE; ++e) { p[e] = expf(p[e] - m); s += p[e]; }
        float inv = 1.f / s, q = 0.f;
#pragma unroll
        for (int e = 0; e < EE; ++e) { p[e] = 0.99f * p[e] * inv + 0.00125f; q += p[e] * p[e]; }
        ssq[t] = q;
        int i1 = 0;
#pragma unroll
        for (int e = 1; e < EE; ++e) if (p[e] > p[i1]) i1 = e;    // lowest idx on tie
        int i2 = (i1 == 0) ? 1 : 0;
#pragma unroll
        for (int e = 0; e < EE; ++e) if (e != i1 && p[e] > p[i2]) i2 = e;
        tk_pack[t] = i1 | (i2 << 4);
        tk_w[t] = p[i1] / (p[i1] + p[i2]);             // w2 = 1 - w1
    }
}

// ---------------- scatter: per-block LDS histogram + 8 global atomics/block ----------------
__global__ __launch_bounds__(256) void scatter_kernel(const int* __restrict__ tk_pack,
                                                      int* __restrict__ counts,
                                                      int* __restrict__ tok_list,
                                                      int* __restrict__ tk_pos) {
    __shared__ int lcnt[EE];
    __shared__ int gbase[EE];
    int tid = threadIdx.x;
    int t = blockIdx.x * 256 + tid;
    if (tid < EE) lcnt[tid] = 0;
    __syncthreads();
    int pk = tk_pack[t];
    int i1 = pk & 15, i2 = pk >> 4;
    int p1 = atomicAdd(&lcnt[i1], 1);
    int p2 = atomicAdd(&lcnt[i2], 1);
    __syncthreads();
    if (tid < EE) gbase[tid] = atomicAdd(&counts[tid], lcnt[tid]);
    __syncthreads();
    int q1 = gbase[i1] + p1, q2 = gbase[i2] + p2;
    tok_list[i1 * BT + q1] = t;
    tok_list[i2 * BT + q2] = t;
    tk_pos[t] = q1 | (q2 << 16);
}

__global__ void offsets_kernel(const int* __restrict__ counts, int* __restrict__ offs) {
    if (threadIdx.x == 0) {
        int a = 0;
        for (int e = 0; e < EE; ++e) { offs[e] = a; a += counts[e]; }
        offs[EE] = a;
    }
}

// ---------------- grouped GEMM: 128x256 tile, BK=64, 8 waves, triple-buffered LDS,
// 2 phases/K-tile (16 MFMA each), counted vmcnt(6), setprio around MFMA ----------------
// A[row][k] (gathered via tok_list if GATHER), WT[e][n][k]; Out[row][n] bf16 (+bias, opt GELU).
template<int NDIM, int KDIM, bool DOGELU, bool GATHER>
__global__ __launch_bounds__(512, 2) void moe_gemm_kernel(
        const unsigned short* __restrict__ Amat, const unsigned short* __restrict__ WT,
        const float* __restrict__ bias, const int* __restrict__ counts,
        const int* __restrict__ offs, const int* __restrict__ tok_list,
        unsigned short* __restrict__ Out) {
    constexpr int NTK = KDIM / 64;          // K tiles
    constexpr int NNT = NDIM / 256;         // N tiles
    int e = blockIdx.x & 7;                 // expert -> XCD pin
    int j = blockIdx.x >> 3;
    int n0 = (j % NNT) * 256;
    int m0 = (j / NNT) * 128;
    int cnt = counts[e];
    if (m0 >= cnt) return;
    int base = offs[e];

    // A slabs: 3 x 8192 shorts (16KB); B slabs: 3 x 16384 shorts (32KB) at +24576. 144KB total.
    __shared__ __align__(16) unsigned short lds[73728];

    int tid = threadIdx.x, l = tid & 63, w = tid >> 6;
    int wm = w >> 2, wn = w & 3;            // wave covers rows wm*64..+63, cols wn*64..+63

    // ---- staging source pointers (per-lane; granule-XOR pre-swizzled source) ----
    int srow = w * 8 + (l >> 3);            // row within a 64-row issue group
    int g    = (l & 7) ^ (l >> 3);          // source granule (16B) for linear LDS dest
    const unsigned short* pA[2];
#pragma unroll
    for (int i = 0; i < 2; ++i) {
        int r = m0 + i * 64 + srow; if (r >= cnt) r = cnt - 1;
        size_t grow = GATHER ? (size_t)tok_list[e * BT + r] : (size_t)(base + r);
        pA[i] = Amat + grow * KDIM + g * 8;
    }
    const unsigned short* pB[4];
#pragma unroll
    for (int i = 0; i < 4; ++i) {
        int nrow = n0 + i * 64 + srow;
        pB[i] = WT + ((size_t)e * NDIM + nrow) * KDIM + g * 8;
    }

    // ---- LDS read bases (shorts); pos undoes the source swizzle; 2-way banks = free ----
    int pos0 = (((l >> 4)) ^ (l & 7)) * 8;          // kk=0
    int pos1 = ((4 + (l >> 4)) ^ (l & 7)) * 8;      // kk=1
    int rdA = (wm * 64 + (l & 15)) * 64;
    int rdB = (wn * 64 + (l & 15)) * 64;

    f32x4 acc[4][4];
#pragma unroll
    for (int i = 0; i < 4; ++i)
#pragma unroll
        for (int q = 0; q < 4; ++q) acc[i][q] = (f32x4){0.f, 0.f, 0.f, 0.f};

    // ---- prologue: stage kt=0 then kt=1 (6 issues each) ----
#pragma unroll
    for (int kt = 0; kt < 2; ++kt) {
#pragma unroll
        for (int i = 0; i < 2; ++i)
            gload16(pA[i] + kt * 64, &lds[kt * 8192 + i * 4096 + w * 512]);
#pragma unroll
        for (int i = 0; i < 4; ++i)
            gload16(pB[i] + kt * 64, &lds[24576 + kt * 16384 + i * 4096 + w * 512]);
    }
    asm volatile("s_waitcnt vmcnt(6)" ::: "memory");   // kt0 landed; kt1 may fly
    phase_fence_barrier();

    int bcur = 0;
    for (int kt = 0; kt < NTK; ++kt) {
        int bstage = bcur + 2; if (bstage >= 3) bstage -= 3;   // (kt+2)%3
        int kst = kt + 2; if (kst > NTK - 1) kst = NTK - 1;    // clamped source (dest never read)
        int ab = bcur * 8192 + rdA;
        int bb = 24576 + bcur * 16384 + rdB;

        // ===== phase A: fm 0-1 x fn 0-3 =====
        bf16x8 af0[2][2], bf[4][2];
#pragma unroll
        for (int fl = 0; fl < 2; ++fl) {
            af0[fl][0] = *(const bf16x8*)&lds[ab + fl * 1024 + pos0];
            af0[fl][1] = *(const bf16x8*)&lds[ab + fl * 1024 + pos1];
        }
#pragma unroll
        for (int fn = 0; fn < 4; ++fn) {
            bf[fn][0] = *(const bf16x8*)&lds[bb + fn * 1024 + pos0];
            bf[fn][1] = *(const bf16x8*)&lds[bb + fn * 1024 + pos1];
        }
        gload16(pA[0] + kst * 64, &lds[bstage * 8192 + w * 512]);
        gload16(pA[1] + kst * 64, &lds[bstage * 8192 + 4096 + w * 512]);
        gload16(pB[0] + kst * 64, &lds[24576 + bstage * 16384 + w * 512]);
        phase_fence_barrier();
        __builtin_amdgcn_s_setprio(1);
#pragma unroll
        for (int fl = 0; fl < 2; ++fl)
#pragma unroll
            for (int fn = 0; fn < 4; ++fn) {
                acc[fl][fn] = __builtin_amdgcn_mfma_f32_16x16x32_bf16(bf[fn][0], af0[fl][0], acc[fl][fn], 0, 0, 0);
                acc[fl][fn] = __builtin_amdgcn_mfma_f32_16x16x32_bf16(bf[fn][1], af0[fl][1], acc[fl][fn], 0, 0, 0);
            }
        __builtin_amdgcn_s_setprio(0);
        phase_fence_barrier();

        // ===== phase B: fm 2-3 x fn 0-3 (reuse bf) =====
        bf16x8 af1[2][2];
#pragma unroll
        for (int fl = 0; fl < 2; ++fl) {
            af1[fl][0] = *(const bf16x8*)&lds[ab + (2 + fl) * 1024 + pos0];
            af1[fl][1] = *(const bf16x8*)&lds[ab + (2 + fl) * 1024 + pos1];
        }
        gload16(pB[1] + kst * 64, &lds[24576 + bstage * 16384 + 4096 + w * 512]);
        gload16(pB[2] + kst * 64, &lds[24576 + bstage * 16384 + 8192 + w * 512]);
        gload16(pB[3] + kst * 64, &lds[24576 + bstage * 16384 + 12288 + w * 512]);
        asm volatile("s_waitcnt vmcnt(6)" ::: "memory");   // kt+1 landed; kt+2's 6 may fly
        phase_fence_barrier();
        __builtin_amdgcn_s_setprio(1);
#pragma unroll
        for (int fl = 0; fl < 2; ++fl)
#pragma unroll
            for (int fn = 0; fn < 4; ++fn) {
                acc[2 + fl][fn] = __builtin_amdgcn_mfma_f32_16x16x32_bf16(bf[fn][0], af1[fl][0], acc[2 + fl][fn], 0, 0, 0);
                acc[2 + fl][fn] = __builtin_amdgcn_mfma_f32_16x16x32_bf16(bf[fn][1], af1[fl][1], acc[2 + fl][fn], 0, 0, 0);
            }
        __builtin_amdgcn_s_setprio(0);
        phase_fence_barrier();

        bcur = (bcur == 2) ? 0 : bcur + 1;
    }

    // ---- epilogue: lane holds 4 consecutive n for token col l&15 ----
    const float* be = bias + e * NDIM;
#pragma unroll
    for (int fm = 0; fm < 4; ++fm) {
        int r = m0 + wm * 64 + fm * 16 + (l & 15);
        if (r >= cnt) continue;
        unsigned short* orow = Out + (size_t)(base + r) * NDIM;
#pragma unroll
        for (int fn = 0; fn < 4; ++fn) {
            int n = n0 + wn * 64 + fn * 16 + (l >> 4) * 4;
            float4 bb4 = *(const float4*)&be[n];
            f32x4 a = acc[fm][fn];
            float v0 = a[0] + bb4.x, v1 = a[1] + bb4.y;
            float v2 = a[2] + bb4.z, v3 = a[3] + bb4.w;
            if (DOGELU) {
                v0 = gelu_fast(v0); v1 = gelu_fast(v1);
                v2 = gelu_fast(v2); v3 = gelu_fast(v3);
            }
            ushort4 pk = { f2bf(v0), f2bf(v1), f2bf(v2), f2bf(v3) };
            *(ushort4*)&orow[n] = pk;
        }
    }
}

// ---------------- combine: out[t] = w1*y[row1] + (1-w1)*y[row2] ----------------
__global__ __launch_bounds__(256) void combine_kernel(
        const unsigned short* __restrict__ ybuf, const int* __restrict__ offs,
        const int* __restrict__ tk_pack, const float* __restrict__ tk_w,
        const int* __restrict__ tk_pos, float* __restrict__ out) {
    int tid = threadIdx.x;
    int t  = blockIdx.x * 2 + (tid >> 7);              // 2 tokens per block
    int lt = tid & 127;                                // 8 floats per thread
    int pk  = tk_pack[t];
    int pos = tk_pos[t];
    float w1 = tk_w[t], w2 = 1.f - w1;
    int r1 = offs[pk & 15] + (pos & 0xffff);
    int r2 = offs[pk >> 4] + (pos >> 16);
    ushort4 a0 = ((const ushort4*)(ybuf + (size_t)r1 * DD))[lt * 2];
    ushort4 a1 = ((const ushort4*)(ybuf + (size_t)r1 * DD))[lt * 2 + 1];
    ushort4 b0 = ((const ushort4*)(ybuf + (size_t)r2 * DD))[lt * 2];
    ushort4 b1 = ((const ushort4*)(ybuf + (size_t)r2 * DD))[lt * 2 + 1];
    float4 o0 = { w1 * bf2f(a0.x) + w2 * bf2f(b0.x), w1 * bf2f(a0.y) + w2 * bf2f(b0.y),
                  w1 * bf2f(a0.z) + w2 * bf2f(b0.z), w1 * bf2f(a0.w) + w2 * bf2f(b0.w) };
    float4 o1 = { w1 * bf2f(a1.x) + w2 * bf2f(b1.x), w1 * bf2f(a1.y) + w2 * bf2f(b1.y),
                  w1 * bf2f(a1.z) + w2 * bf2f(b1.z), w1 * bf2f(a1.w) + w2 * bf2f(b1.w) };
    float4* orow = (float4*)(out + (size_t)t * DD);
    orow[lt * 2]     = o0;
    orow[lt * 2 + 1] = o1;
}

// ---------------- aux = mean(sum probs^2) * E ----------------
__global__ void aux_kernel(const float* __restrict__ ssq, float* __restrict__ out_aux) {
    __shared__ float red[4];
    float s = 0.f;
    for (int i = threadIdx.x; i < BT; i += 256) s += ssq[i];
#pragma unroll
    for (int off = 32; off; off >>= 1) s += __shfl_xor(s, off, 64);
    if ((threadIdx.x & 63) == 0) red[threadIdx.x >> 6] = s;
    __syncthreads();
    if (threadIdx.x == 0)
        out_aux[0] = (red[0] + red[1] + red[2] + red[3]) * (float)EE / (float)BT;
}

extern "C" void kernel_launch(void* const* d_in, const int* in_sizes, int n_in,
                              void* d_out, int out_size, void* d_ws, size_t ws_size,
                              hipStream_t stream) {
    const float* x  = (const float*)d_in[0];
    const float* Wg = (const float*)d_in[1];
    const float* bg = (const float*)d_in[2];
    const float* W1 = (const float*)d_in[3];
    const float* b1 = (const float*)d_in[4];
    const float* W2 = (const float*)d_in[5];
    const float* b2 = (const float*)d_in[6];
    float* out = (float*)d_out;

    char* wsb = (char*)d_ws;
    int*   counts  = (int*)wsb;                         // 0 .. 64
    int*   offs    = (int*)(wsb + 64);                  // 64 .. 256
    int*   tok     = (int*)(wsb + 256);                 // 8*8192*4 -> 262400
    float* ssq     = (float*)(wsb + 262400);            // 32 KB -> 295168
    int*   tk_pack = (int*)(wsb + 295168);              // 32 KB -> 327936
    float* tk_w    = (float*)(wsb + 327936);            // 32 KB -> 360704
    int*   tk_pos  = (int*)(wsb + 360704);              // 32 KB -> 393472
    unsigned short* xbf  = (unsigned short*)(wsb + 393472);      // 16 MB -> 17170688
    unsigned short* W1T  = (unsigned short*)(wsb + 17170688);    // 32 MB -> 50725120
    unsigned short* W2T  = (unsigned short*)(wsb + 50725120);    // 32 MB -> 84279552
    unsigned short* hbuf = (unsigned short*)(wsb + 84279552);    // 64 MB -> 151388416
    // ybuf (33.5 MB bf16) overlays xbf+W1T — both dead once gemm1 has run
    unsigned short* ybuf = (unsigned short*)(wsb + 393472);

    hipMemsetAsync(wsb, 0, 64, stream);                 // counts only

    transpose_cvt_kernel<<<dim3(HH / 64, DD / 64, EE), 256, 0, stream>>>(W1, W1T, DD, HH);
    transpose_cvt_kernel<<<dim3(DD / 64, HH / 64, EE), 256, 0, stream>>>(W2, W2T, HH, DD);
    gating_kernel<<<BT / 4, 256, 0, stream>>>(x, Wg, bg, tk_pack, tk_w, ssq, xbf);
    scatter_kernel<<<BT / 256, 256, 0, stream>>>(tk_pack, counts, tok, tk_pos);
    offsets_kernel<<<1, 64, 0, stream>>>(counts, offs);
    moe_gemm_kernel<HH, DD, true, true><<<8 * (HH / 256) * (BT / 128), 512, 0, stream>>>(
        xbf, W1T, b1, counts, offs, tok, hbuf);
    moe_gemm_kernel<DD, HH, false, false><<<8 * (DD / 256) * (BT / 128), 512, 0, stream>>>(
        hbuf, W2T, b2, counts, offs, tok, ybuf);
    combine_kernel<<<BT / 2, 256, 0, stream>>>(ybuf, offs, tk_pack, tk_w, tk_pos, out);
    aux_kernel<<<1, 256, 0, stream>>>(ssq, out + (size_t)BT * DD);
}

// Round 7
// 299.277 us; speedup vs baseline: 1.0725x; 1.0725x over previous
//
#include <hip/hip_runtime.h>
#include <hip/hip_bf16.h>
#include <cmath>

#define BT 8192      // B*T tokens
#define DD 1024      // model dim
#define EE 8         // experts
#define HH 2048      // hidden

typedef __attribute__((ext_vector_type(8))) short bf16x8;
typedef __attribute__((ext_vector_type(4))) float f32x4;

__device__ __forceinline__ unsigned short f2bf(float f) {
    union { float f; unsigned u; } v; v.f = f;
    unsigned r = v.u + 0x7FFFu + ((v.u >> 16) & 1u);   // RNE
    return (unsigned short)(r >> 16);
}

__device__ __forceinline__ float bf2f(unsigned short s) {
    union { unsigned u; float f; } v; v.u = ((unsigned)s) << 16;
    return v.f;
}

// tanh-form GELU via sigmoid: max |diff vs exact erf-GELU| ~5e-4
__device__ __forceinline__ float gelu_fast(float x) {
    float z = x * (1.5957691216f + 0.071354816f * x * x);
    return x / (1.f + __expf(-z));
}

// async global->LDS, 16B per lane; LDS dest = wave-uniform base + lane*16
__device__ __forceinline__ void gload16(const void* g, void* l) {
    __builtin_amdgcn_global_load_lds(
        (const __attribute__((address_space(1))) void*)g,
        (__attribute__((address_space(3))) void*)l, 16, 0, 0);
}

__device__ __forceinline__ void fence_barrier() {
    __builtin_amdgcn_sched_barrier(0);
    __builtin_amdgcn_s_barrier();
    __builtin_amdgcn_sched_barrier(0);
}

// ---------------- prepass: both W transposes fused; fp32 [R][C] -> bf16 [C][R] ----------------
__global__ __launch_bounds__(256) void transpose_both_kernel(
        const float* __restrict__ W1, const float* __restrict__ W2,
        unsigned short* __restrict__ W1T, unsigned short* __restrict__ W2T) {
    int bid = blockIdx.x;
    const float* in; unsigned short* out; int R, C, r0, c0, e;
    if (bid < 4096) {            // W1 [8][1024][2048] -> [8][2048][1024]
        in = W1; out = W1T; R = DD; C = HH;
        e = bid & 7; int t = bid >> 3; c0 = (t & 31) * 64; r0 = (t >> 5) * 64;
    } else {                     // W2 [8][2048][1024] -> [8][1024][2048]
        bid -= 4096;
        in = W2; out = W2T; R = HH; C = DD;
        e = bid & 7; int t = bid >> 3; c0 = (t & 15) * 64; r0 = (t >> 4) * 64;
    }
    __shared__ unsigned short t[64][66];
    int tid = threadIdx.x;
    int ci = (tid & 31) * 2;                 // float2 along C
    int ri = tid >> 5;                       // 8 rows per pass
    const float* src = in + ((size_t)e * R + r0) * C + c0;
#pragma unroll
    for (int j = 0; j < 8; ++j) {
        int r = ri + j * 8;
        float2 v = *(const float2*)&src[(size_t)r * C + ci];
        t[ci][r] = f2bf(v.x); t[ci + 1][r] = f2bf(v.y);
    }
    __syncthreads();
    int r2 = (tid & 15) * 4, c2 = tid >> 4;
    unsigned short* dst = out + ((size_t)e * C + c0) * R + r0;
#pragma unroll
    for (int j = 0; j < 4; ++j) {
        int c = c2 + j * 16;
        ushort4 v = { t[c][r2], t[c][r2 + 1], t[c][r2 + 2], t[c][r2 + 3] };
        *(ushort4*)&dst[(size_t)c * R + r2] = v;
    }
}

// ---------------- gating (+ fused x->bf16 convert): NO atomics ----------------
__global__ void gating_kernel(const float* __restrict__ x, const float* __restrict__ Wg,
                              const float* __restrict__ bg, int* __restrict__ tk_pack,
                              float* __restrict__ tk_w, float* __restrict__ ssq,
                              unsigned short* __restrict__ xbf) {
    int lane = threadIdx.x & 63;
    int wid  = threadIdx.x >> 6;
    int t = blockIdx.x * 4 + wid;           // one wave per token
    const float* xr = x + (size_t)t * DD;
    unsigned* xbr = (unsigned*)(xbf + (size_t)t * DD);
    float acc[EE];
#pragma unroll
    for (int e = 0; e < EE; ++e) acc[e] = 0.f;
    for (int d = lane * 2; d < DD; d += 128) {
        float2 xv = *(const float2*)&xr[d];
        xbr[d >> 1] = (unsigned)f2bf(xv.x) | ((unsigned)f2bf(xv.y) << 16);
        const float* wr = Wg + d * EE;
#pragma unroll
        for (int e = 0; e < EE; ++e) acc[e] += xv.x * wr[e] + xv.y * wr[e + EE];
    }
#pragma unroll
    for (int off = 32; off; off >>= 1)
#pragma unroll
        for (int e = 0; e < EE; ++e) acc[e] += __shfl_xor(acc[e], off, 64);

    if (lane == 0) {
        float p[EE]; float m = -1e30f;
#pragma unroll
        for (int e = 0; e < EE; ++e) { p[e] = acc[e] + bg[e]; m = fmaxf(m, p[e]); }
        float s = 0.f;
#pragma unroll
        for (int e = 0; e < EE; ++e) { p[e] = expf(p[e] - m); s += p[e]; }
        float inv = 1.f / s, q = 0.f;
#pragma unroll
        for (int e = 0; e < EE; ++e) { p[e] = 0.99f * p[e] * inv + 0.00125f; q += p[e] * p[e]; }
        ssq[t] = q;
        int i1 = 0;
#pragma unroll
        for (int e = 1; e < EE; ++e) if (p[e] > p[i1]) i1 = e;    // lowest idx on tie
        int i2 = (i1 == 0) ? 1 : 0;
#pragma unroll
        for (int e = 0; e < EE; ++e) if (e != i1 && p[e] > p[i2]) i2 = e;
        tk_pack[t] = i1 | (i2 << 4);
        tk_w[t] = p[i1] / (p[i1] + p[i2]);             // w2 = 1 - w1
    }
}

// ---------------- scatter: per-block LDS histogram + 8 global atomics/block ----------------
__global__ __launch_bounds__(256) void scatter_kernel(const int* __restrict__ tk_pack,
                                                      int* __restrict__ counts,
                                                      int* __restrict__ tok_list,
                                                      int* __restrict__ tk_pos) {
    __shared__ int lcnt[EE];
    __shared__ int gbase[EE];
    int tid = threadIdx.x;
    int t = blockIdx.x * 256 + tid;
    if (tid < EE) lcnt[tid] = 0;
    __syncthreads();
    int pk = tk_pack[t];
    int i1 = pk & 15, i2 = pk >> 4;
    int p1 = atomicAdd(&lcnt[i1], 1);
    int p2 = atomicAdd(&lcnt[i2], 1);
    __syncthreads();
    if (tid < EE) gbase[tid] = atomicAdd(&counts[tid], lcnt[tid]);
    __syncthreads();
    int q1 = gbase[i1] + p1, q2 = gbase[i2] + p2;
    tok_list[i1 * BT + q1] = t;
    tok_list[i2 * BT + q2] = t;
    tk_pos[t] = q1 | (q2 << 16);
}

__global__ void offsets_kernel(const int* __restrict__ counts, int* __restrict__ offs) {
    if (threadIdx.x == 0) {
        int a = 0;
        for (int e = 0; e < EE; ++e) { offs[e] = a; a += counts[e]; }
        offs[EE] = a;
    }
}

// ---------------- grouped GEMM: 128x128 tile, 256 thr, BK=32, TRIPLE-buffered LDS (48KB),
// counted vmcnt(8) (never 0), 2-iteration prefetch distance, setprio on MFMA ----------------
// A[row][k] (gathered if GATHER), WT[e][n][k]; Out[row][n] bf16 (+bias, opt GELU).
template<int NDIM, int KDIM, bool DOGELU, bool GATHER>
__global__ __launch_bounds__(256) void moe_gemm_kernel(
        const unsigned short* __restrict__ Amat, const unsigned short* __restrict__ WT,
        const float* __restrict__ bias, const int* __restrict__ counts,
        const int* __restrict__ offs, const int* __restrict__ tok_list,
        unsigned short* __restrict__ Out) {
    constexpr int NTK = KDIM / 32;          // K tiles of 32
    constexpr int NNT = NDIM / 128;         // N tiles
    int p = blockIdx.x;
    int e = p & 7;                          // expert -> XCD pin
    int j = p >> 3;
    int n0 = (j % NNT) * 128;
    int m0 = (j / NNT) * 128;
    int cnt = counts[e];
    if (m0 >= cnt) return;
    int base = offs[e];

    // A: 3 x 4096 shorts @0; B: 3 x 4096 shorts @12288. 48KB -> 3 blocks/CU.
    __shared__ __align__(16) unsigned short lds[24576];

    int tid = threadIdx.x, l = tid & 63, w = tid >> 6;
    int wr = w >> 1, wc = w & 1;

    // staging map (identical to proven r5): wave w covers rows w*32..w*32+31, 2 calls/operand
    int rs0 = w * 32 + (l >> 2);
    int rs1 = rs0 + 16;
    int g0  = (l & 3) ^ ((rs0 >> 1) & 3);      // swizzled source granule
    int g1  = (l & 3) ^ ((rs1 >> 1) & 3);
    int ra0 = m0 + rs0; if (ra0 >= cnt) ra0 = cnt - 1;
    int ra1 = m0 + rs1; if (ra1 >= cnt) ra1 = cnt - 1;
    size_t gr0 = GATHER ? (size_t)tok_list[e * BT + ra0] : (size_t)(base + ra0);
    size_t gr1 = GATHER ? (size_t)tok_list[e * BT + ra1] : (size_t)(base + ra1);
    const unsigned short* pa0 = Amat + gr0 * KDIM + g0 * 8;
    const unsigned short* pa1 = Amat + gr1 * KDIM + g1 * 8;
    const unsigned short* pb0 = WT + ((size_t)e * NDIM + n0 + rs0) * KDIM + g0 * 8;
    const unsigned short* pb1 = WT + ((size_t)e * NDIM + n0 + rs1) * KDIM + g1 * 8;

    int slot = (l >> 4) ^ ((l >> 1) & 3);      // swizzled read granule
    int arow = wr * 64 + (l & 15);
    int brow = wc * 64 + (l & 15);

    f32x4 acc[4][4];
#pragma unroll
    for (int i = 0; i < 4; ++i)
#pragma unroll
        for (int q = 0; q < 4; ++q) acc[i][q] = (f32x4){0.f, 0.f, 0.f, 0.f};

    // prologue: kt=0 -> buf0, kt=1 -> buf1 (8 loads in flight)
#pragma unroll
    for (int t = 0; t < 2; ++t) {
        gload16(pa0 + t * 32, &lds[t * 4096 + w * 1024]);
        gload16(pa1 + t * 32, &lds[t * 4096 + w * 1024 + 512]);
        gload16(pb0 + t * 32, &lds[12288 + t * 4096 + w * 1024]);
        gload16(pb1 + t * 32, &lds[12288 + t * 4096 + w * 1024 + 512]);
    }

    int bcur = 0;
    for (int kt = 0; kt < NTK; ++kt) {
        int bst = bcur + 2; if (bst >= 3) bst -= 3;     // stage buffer (kt+2)%3
        int kof = kt + 2; if (kof > NTK - 1) kof = NTK - 1;   // clamped src; dest never read
        kof *= 32;
        gload16(pa0 + kof, &lds[bst * 4096 + w * 1024]);
        gload16(pa1 + kof, &lds[bst * 4096 + w * 1024 + 512]);
        gload16(pb0 + kof, &lds[12288 + bst * 4096 + w * 1024]);
        gload16(pb1 + kof, &lds[12288 + bst * 4096 + w * 1024 + 512]);

        asm volatile("s_waitcnt vmcnt(8)" ::: "memory");   // drain tile kt only; 8 stay in flight
        fence_barrier();                                   // buf bcur visible to all waves

        int ab = bcur * 4096 + arow * 32 + slot * 8;
        int bb = 12288 + bcur * 4096 + brow * 32 + slot * 8;
        bf16x8 af[4], bf[4];
#pragma unroll
        for (int f = 0; f < 4; ++f) {
            af[f] = *(const bf16x8*)&lds[ab + f * 512];
            bf[f] = *(const bf16x8*)&lds[bb + f * 512];
        }
        asm volatile("s_waitcnt lgkmcnt(0)" ::: "memory"); // all reads landed (WAR for restage)
        fence_barrier();

        __builtin_amdgcn_s_setprio(1);
#pragma unroll
        for (int fm = 0; fm < 4; ++fm)
#pragma unroll
            for (int fn = 0; fn < 4; ++fn)   // swapped: D[n][token]
                acc[fm][fn] = __builtin_amdgcn_mfma_f32_16x16x32_bf16(bf[fn], af[fm], acc[fm][fn], 0, 0, 0);
        __builtin_amdgcn_s_setprio(0);

        bcur = bcur + 1; if (bcur == 3) bcur = 0;
    }

    // epilogue: lane holds 4 consecutive n for token col l&15
    const float* be = bias + e * NDIM;
#pragma unroll
    for (int fm = 0; fm < 4; ++fm) {
        int r = m0 + wr * 64 + fm * 16 + (l & 15);
        if (r >= cnt) continue;
        unsigned short* orow = Out + (size_t)(base + r) * NDIM;
#pragma unroll
        for (int fn = 0; fn < 4; ++fn) {
            int n = n0 + wc * 64 + fn * 16 + (l >> 4) * 4;
            float4 bb4 = *(const float4*)&be[n];
            f32x4 a = acc[fm][fn];
            float v0 = a[0] + bb4.x, v1 = a[1] + bb4.y;
            float v2 = a[2] + bb4.z, v3 = a[3] + bb4.w;
            if (DOGELU) {
                v0 = gelu_fast(v0); v1 = gelu_fast(v1);
                v2 = gelu_fast(v2); v3 = gelu_fast(v3);
            }
            ushort4 pk = { f2bf(v0), f2bf(v1), f2bf(v2), f2bf(v3) };
            *(ushort4*)&orow[n] = pk;
        }
    }
}

// ---------------- combine: out[t] = w1*y[row1] + (1-w1)*y[row2] ----------------
__global__ __launch_bounds__(256) void combine_kernel(
        const unsigned short* __restrict__ ybuf, const int* __restrict__ offs,
        const int* __restrict__ tk_pack, const float* __restrict__ tk_w,
        const int* __restrict__ tk_pos, float* __restrict__ out) {
    int tid = threadIdx.x;
    int t  = blockIdx.x * 2 + (tid >> 7);              // 2 tokens per block
    int lt = tid & 127;                                // 8 floats per thread
    int pk  = tk_pack[t];
    int pos = tk_pos[t];
    float w1 = tk_w[t], w2 = 1.f - w1;
    int r1 = offs[pk & 15] + (pos & 0xffff);
    int r2 = offs[pk >> 4] + (pos >> 16);
    ushort4 a0 = ((const ushort4*)(ybuf + (size_t)r1 * DD))[lt * 2];
    ushort4 a1 = ((const ushort4*)(ybuf + (size_t)r1 * DD))[lt * 2 + 1];
    ushort4 b0 = ((const ushort4*)(ybuf + (size_t)r2 * DD))[lt * 2];
    ushort4 b1 = ((const ushort4*)(ybuf + (size_t)r2 * DD))[lt * 2 + 1];
    float4 o0 = { w1 * bf2f(a0.x) + w2 * bf2f(b0.x), w1 * bf2f(a0.y) + w2 * bf2f(b0.y),
                  w1 * bf2f(a0.z) + w2 * bf2f(b0.z), w1 * bf2f(a0.w) + w2 * bf2f(b0.w) };
    float4 o1 = { w1 * bf2f(a1.x) + w2 * bf2f(b1.x), w1 * bf2f(a1.y) + w2 * bf2f(b1.y),
                  w1 * bf2f(a1.z) + w2 * bf2f(b1.z), w1 * bf2f(a1.w) + w2 * bf2f(b1.w) };
    float4* orow = (float4*)(out + (size_t)t * DD);
    orow[lt * 2]     = o0;
    orow[lt * 2 + 1] = o1;
}

// ---------------- aux = mean(sum probs^2) * E ----------------
__global__ void aux_kernel(const float* __restrict__ ssq, float* __restrict__ out_aux) {
    __shared__ float red[4];
    float s = 0.f;
    for (int i = threadIdx.x; i < BT; i += 256) s += ssq[i];
#pragma unroll
    for (int off = 32; off; off >>= 1) s += __shfl_xor(s, off, 64);
    if ((threadIdx.x & 63) == 0) red[threadIdx.x >> 6] = s;
    __syncthreads();
    if (threadIdx.x == 0)
        out_aux[0] = (red[0] + red[1] + red[2] + red[3]) * (float)EE / (float)BT;
}

extern "C" void kernel_launch(void* const* d_in, const int* in_sizes, int n_in,
                              void* d_out, int out_size, void* d_ws, size_t ws_size,
                              hipStream_t stream) {
    const float* x  = (const float*)d_in[0];
    const float* Wg = (const float*)d_in[1];
    const float* bg = (const float*)d_in[2];
    const float* W1 = (const float*)d_in[3];
    const float* b1 = (const float*)d_in[4];
    const float* W2 = (const float*)d_in[5];
    const float* b2 = (const float*)d_in[6];
    float* out = (float*)d_out;

    char* wsb = (char*)d_ws;
    int*   counts  = (int*)wsb;                         // 0 .. 64
    int*   offs    = (int*)(wsb + 64);                  // 64 .. 256
    int*   tok     = (int*)(wsb + 256);                 // 8*8192*4 -> 262400
    float* ssq     = (float*)(wsb + 262400);            // 32 KB -> 295168
    int*   tk_pack = (int*)(wsb + 295168);              // 32 KB -> 327936
    float* tk_w    = (float*)(wsb + 327936);            // 32 KB -> 360704
    int*   tk_pos  = (int*)(wsb + 360704);              // 32 KB -> 393472
    unsigned short* xbf  = (unsigned short*)(wsb + 393472);      // 16 MB -> 17170688
    unsigned short* W1T  = (unsigned short*)(wsb + 17170688);    // 32 MB -> 50725120
    unsigned short* W2T  = (unsigned short*)(wsb + 50725120);    // 32 MB -> 84279552
    unsigned short* hbuf = (unsigned short*)(wsb + 84279552);    // 64 MB -> 151388416
    // ybuf (33.5 MB bf16) overlays xbf+W1T — both dead once gemm1 has run
    unsigned short* ybuf = (unsigned short*)(wsb + 393472);

    hipMemsetAsync(wsb, 0, 64, stream);                 // counts only

    gating_kernel<<<BT / 4, 256, 0, stream>>>(x, Wg, bg, tk_pack, tk_w, ssq, xbf);
    transpose_both_kernel<<<8192, 256, 0, stream>>>(W1, W2, W1T, W2T);
    scatter_kernel<<<BT / 256, 256, 0, stream>>>(tk_pack, counts, tok, tk_pos);
    offsets_kernel<<<1, 64, 0, stream>>>(counts, offs);
    moe_gemm_kernel<HH, DD, true, true><<<8 * (HH / 128) * (BT / 128), 256, 0, stream>>>(
        xbf, W1T, b1, counts, offs, tok, hbuf);
    moe_gemm_kernel<DD, HH, false, false><<<8 * (DD / 128) * (BT / 128), 256, 0, stream>>>(
        hbuf, W2T, b2, counts, offs, tok, ybuf);
    combine_kernel<<<BT / 2, 256, 0, stream>>>(ybuf, offs, tk_pack, tk_w, tk_pos, out);
    aux_kernel<<<1, 256, 0, stream>>>(ssq, out + (size_t)BT * DD);
}